// Round 1
// baseline (1223.657 us; speedup 1.0000x reference)
//
#include <hip/hip_runtime.h>

// Problem constants
#define NLAT 192      // K (latitude rings)
#define MM   192      // zonal wavenumbers kept (M = TRUNC+1)
#define LL   192      // l dimension
#define PMAX 404      // max ring length
#define NGRID 41088
#define BC   1024     // BATCH*CHAN = 16*64
#define TWO_PI_F 6.2831853071795864769f

// ---------------------------------------------------------------------------
// Stage 1: per-ring DFT.  re/im[m][k][bc_local] = 2pi * sum_p x[bc][slon+p]*basis[k][p][m]
// Grid: (bcc/64, 3 m-tiles, 192 k).  Block 256.  64(bc) x 64(m) tile, 4x4 micro.
// ---------------------------------------------------------------------------
__global__ __launch_bounds__(256) void sht_stage1(
    const float* __restrict__ x,
    const float* __restrict__ cosb,
    const float* __restrict__ sinb,
    const int*   __restrict__ ring,
    float* __restrict__ ws,        // re at 0, im at MM*NLAT*bcc
    int bc0, int bcc)
{
    const int k   = blockIdx.z;
    const int m0  = blockIdx.y * 64;
    const int bct = blockIdx.x * 64;           // bc tile start within chunk
    const int tid = threadIdx.x;
    const int tx = tid & 15;                    // -> bc micro (4*tx + i)
    const int ty = tid >> 4;                    // -> m  micro (4*ty + j)

    const int slon = ring[k * PMAX];
    const int nlon = ring[k * PMAX + PMAX - 1] - slon + 1;

    float* __restrict__ re_ws = ws;
    float* __restrict__ im_ws = ws + (size_t)MM * NLAT * bcc;

    // Basis is identically zero for m > nlon/2: skip compute, write zeros.
    if (m0 > (nlon >> 1)) {
        float4 z = {0.f, 0.f, 0.f, 0.f};
#pragma unroll
        for (int j = 0; j < 4; ++j) {
            int m = m0 + 4 * ty + j;
            size_t base = ((size_t)m * NLAT + k) * bcc + bct + 4 * tx;
            *(float4*)&re_ws[base] = z;
            *(float4*)&im_ws[base] = z;
        }
        return;
    }

    __shared__ float xs[16][68];   // [p][bc]  (stride 68: 16B-aligned rows, 2-way banks)
    __shared__ float cs[16][64];   // [p][m]
    __shared__ float ss[16][64];

    float accr[4][4] = {{0.f}};
    float acci[4][4] = {{0.f}};

    for (int p0 = 0; p0 < nlon; p0 += 16) {
        // ---- load x tile: 64 bc x 16 p (float4 along p; nlon % 4 == 0 always) ----
        {
            int pq = (tid & 3) * 4;            // p offset within chunk
            int bl = tid >> 2;                 // 0..63 bc within tile
            int p  = p0 + pq;
            float4 v = {0.f, 0.f, 0.f, 0.f};
            if (p < nlon)
                v = *(const float4*)(x + (size_t)(bc0 + bct + bl) * NGRID + slon + p);
            xs[pq + 0][bl] = v.x;
            xs[pq + 1][bl] = v.y;
            xs[pq + 2][bl] = v.z;
            xs[pq + 3][bl] = v.w;
        }
        // ---- load basis tiles: 16 p x 64 m (float4 along m) ----
        {
            int mq = (tid & 15) * 4;
            int pl = tid >> 4;                 // 0..15
            int p  = p0 + pl;
            float4 c = {0.f, 0.f, 0.f, 0.f};
            float4 s = {0.f, 0.f, 0.f, 0.f};
            if (p < PMAX) {
                size_t off = ((size_t)k * PMAX + p) * MM + m0 + mq;
                c = *(const float4*)(cosb + off);
                s = *(const float4*)(sinb + off);
            }
            *(float4*)&cs[pl][mq] = c;
            *(float4*)&ss[pl][mq] = s;
        }
        __syncthreads();

#pragma unroll
        for (int pp = 0; pp < 16; ++pp) {
            float xv[4], cv[4], sv[4];
            *(float4*)xv = *(const float4*)&xs[pp][4 * tx];
            *(float4*)cv = *(const float4*)&cs[pp][4 * ty];
            *(float4*)sv = *(const float4*)&ss[pp][4 * ty];
#pragma unroll
            for (int i = 0; i < 4; ++i)
#pragma unroll
                for (int j = 0; j < 4; ++j) {
                    accr[i][j] += xv[i] * cv[j];
                    acci[i][j] += xv[i] * sv[j];
                }
        }
        __syncthreads();
    }

#pragma unroll
    for (int j = 0; j < 4; ++j) {
        int m = m0 + 4 * ty + j;
        size_t base = ((size_t)m * NLAT + k) * bcc + bct + 4 * tx;
        float4 r = {accr[0][j] * TWO_PI_F, accr[1][j] * TWO_PI_F,
                    accr[2][j] * TWO_PI_F, accr[3][j] * TWO_PI_F};
        float4 s = {acci[0][j] * TWO_PI_F, acci[1][j] * TWO_PI_F,
                    acci[2][j] * TWO_PI_F, acci[3][j] * TWO_PI_F};
        *(float4*)&re_ws[base] = r;
        *(float4*)&im_ws[base] = s;
    }
}

// ---------------------------------------------------------------------------
// Stage 2: out[bc][l][m][ri] = sum_k re/im[m][k][bc] * weight[m][l][k]
// Grid: (bcc/64, 3 l-tiles, 192 m).  Block 256.  64(bc) x 64(l) tile, 4x4 micro.
// weight[m][l][k] == 0 for l < m  ->  l-tiles entirely below the diagonal
// just write zeros.
// ---------------------------------------------------------------------------
__global__ __launch_bounds__(256) void sht_stage2(
    const float* __restrict__ ws,
    const float* __restrict__ weight,
    float* __restrict__ out,
    int bc0, int bcc)
{
    const int m   = blockIdx.z;
    const int l0  = blockIdx.y * 64;
    const int bct = blockIdx.x * 64;
    const int tid = threadIdx.x;
    const int tx = tid & 15;                   // -> bc micro
    const int ty = tid >> 4;                   // -> l micro

    if (l0 + 63 < m) {
        // entire tile is zero (weight[m][l][:] == 0 for all l in tile)
#pragma unroll
        for (int i = 0; i < 4; ++i)
#pragma unroll
            for (int j = 0; j < 4; ++j) {
                int bc = bc0 + bct + 4 * tx + i;
                int l  = l0 + 4 * ty + j;
                size_t o = (((size_t)bc * LL + l) * MM + m) * 2;
                float2 z = {0.f, 0.f};
                *(float2*)&out[o] = z;
            }
        return;
    }

    const float* __restrict__ re_ws = ws;
    const float* __restrict__ im_ws = ws + (size_t)MM * NLAT * bcc;

    __shared__ float rs[16][64];   // [k][bc]
    __shared__ float is_[16][64];
    __shared__ float wl[16][68];   // [k][l]  padded

    float accr[4][4] = {{0.f}};
    float acci[4][4] = {{0.f}};

    for (int k0 = 0; k0 < NLAT; k0 += 16) {
        // re/im tiles: 16 k x 64 bc (coalesced along bc)
        {
            int bl = tid & 63;
            int kk = tid >> 6;                 // 0..3
#pragma unroll
            for (int kp = 0; kp < 4; ++kp) {
                int row = kk + kp * 4;
                size_t off = ((size_t)m * NLAT + k0 + row) * bcc + bct + bl;
                rs[row][bl]  = re_ws[off];
                is_[row][bl] = im_ws[off];
            }
        }
        // weight tile: 64 l x 16 k, transposed into wl[k][l]
        {
            int kk = tid & 15;
            int ll = tid >> 4;                 // 0..15
#pragma unroll
            for (int lp = 0; lp < 4; ++lp) {
                int l = l0 + ll + lp * 16;
                wl[kk][ll + lp * 16] = weight[((size_t)m * LL + l) * NLAT + k0 + kk];
            }
        }
        __syncthreads();

#pragma unroll
        for (int kk = 0; kk < 16; ++kk) {
            float rv[4], iv[4], wv[4];
            *(float4*)rv = *(const float4*)&rs[kk][4 * tx];
            *(float4*)iv = *(const float4*)&is_[kk][4 * tx];
            *(float4*)wv = *(const float4*)&wl[kk][4 * ty];
#pragma unroll
            for (int i = 0; i < 4; ++i)
#pragma unroll
                for (int j = 0; j < 4; ++j) {
                    accr[i][j] += rv[i] * wv[j];
                    acci[i][j] += iv[i] * wv[j];
                }
        }
        __syncthreads();
    }

#pragma unroll
    for (int i = 0; i < 4; ++i)
#pragma unroll
        for (int j = 0; j < 4; ++j) {
            int bc = bc0 + bct + 4 * tx + i;
            int l  = l0 + 4 * ty + j;
            size_t o = (((size_t)bc * LL + l) * MM + m) * 2;
            float2 v = {accr[i][j], acci[i][j]};
            *(float2*)&out[o] = v;
        }
}

// ---------------------------------------------------------------------------
extern "C" void kernel_launch(void* const* d_in, const int* in_sizes, int n_in,
                              void* d_out, int out_size, void* d_ws, size_t ws_size,
                              hipStream_t stream)
{
    const float* x      = (const float*)d_in[0];
    const float* weight = (const float*)d_in[1];
    const float* cosb   = (const float*)d_in[2];
    const float* sinb   = (const float*)d_in[3];
    const int*   ring   = (const int*)d_in[4];
    float* out = (float*)d_out;
    float* wsf = (float*)d_ws;

    // Intermediate (re+im) needs 2*MM*NLAT*bcc floats.  Chunk bc until it fits.
    const size_t per_bc = 2ull * MM * NLAT * sizeof(float);   // 294912 B per bc column
    int chunk = BC;
    while ((size_t)chunk * per_bc > ws_size && chunk > 64) chunk >>= 1;

    for (int bc0 = 0; bc0 < BC; bc0 += chunk) {
        dim3 grid(chunk / 64, 3, NLAT);
        hipLaunchKernelGGL(sht_stage1, grid, dim3(256), 0, stream,
                           x, cosb, sinb, ring, wsf, bc0, chunk);
        dim3 grid2(chunk / 64, 3, MM);
        hipLaunchKernelGGL(sht_stage2, grid2, dim3(256), 0, stream,
                           wsf, weight, out, bc0, chunk);
    }
}

// Round 2
// 1010.719 us; speedup vs baseline: 1.2107x; 1.2107x over previous
//
#include <hip/hip_runtime.h>

// Problem constants
#define NLAT 192      // K (latitude rings)
#define MM   192      // zonal wavenumbers kept (M = TRUNC+1)
#define LL   192      // l dimension
#define PMAX 404      // max ring length
#define NGRID 41088
#define BC   1024     // BATCH*CHAN = 16*64
#define TWO_PI_F 6.2831853071795864769f

// ---------------------------------------------------------------------------
// Stage 1: per-ring DFT.  re/im[m][k][bc_local] = 2pi * sum_p x[bc][slon+p]*basis[k][p][m]
// Grid: (bcc/64, 3 m-tiles, 192 k).  Block 256.  64(bc) x 64(m) tile, 4x4 micro.
// ---------------------------------------------------------------------------
__global__ __launch_bounds__(256) void sht_stage1(
    const float* __restrict__ x,
    const float* __restrict__ cosb,
    const float* __restrict__ sinb,
    const int*   __restrict__ ring,
    float* __restrict__ ws,        // re at 0, im at MM*NLAT*bcc
    int bc0, int bcc)
{
    const int k   = blockIdx.z;
    const int m0  = blockIdx.y * 64;
    const int bct = blockIdx.x * 64;           // bc tile start within chunk
    const int tid = threadIdx.x;
    const int tx = tid & 15;                    // -> bc micro (4*tx + i)
    const int ty = tid >> 4;                    // -> m  micro (4*ty + j)

    const int slon = ring[k * PMAX];
    const int nlon = ring[k * PMAX + PMAX - 1] - slon + 1;

    float* __restrict__ re_ws = ws;
    float* __restrict__ im_ws = ws + (size_t)MM * NLAT * bcc;

    // Basis is identically zero for m > nlon/2: skip compute, write zeros.
    if (m0 > (nlon >> 1)) {
        float4 z = {0.f, 0.f, 0.f, 0.f};
#pragma unroll
        for (int j = 0; j < 4; ++j) {
            int m = m0 + 4 * ty + j;
            size_t base = ((size_t)m * NLAT + k) * bcc + bct + 4 * tx;
            *(float4*)&re_ws[base] = z;
            *(float4*)&im_ws[base] = z;
        }
        return;
    }

    __shared__ float xs[16][68];   // [p][bc]
    __shared__ float cs[16][64];   // [p][m]
    __shared__ float ss[16][64];

    float accr[4][4] = {{0.f}};
    float acci[4][4] = {{0.f}};

    for (int p0 = 0; p0 < nlon; p0 += 16) {
        {
            int pq = (tid & 3) * 4;            // p offset within chunk
            int bl = tid >> 2;                 // 0..63 bc within tile
            int p  = p0 + pq;
            float4 v = {0.f, 0.f, 0.f, 0.f};
            if (p < nlon)
                v = *(const float4*)(x + (size_t)(bc0 + bct + bl) * NGRID + slon + p);
            xs[pq + 0][bl] = v.x;
            xs[pq + 1][bl] = v.y;
            xs[pq + 2][bl] = v.z;
            xs[pq + 3][bl] = v.w;
        }
        {
            int mq = (tid & 15) * 4;
            int pl = tid >> 4;                 // 0..15
            int p  = p0 + pl;
            float4 c = {0.f, 0.f, 0.f, 0.f};
            float4 s = {0.f, 0.f, 0.f, 0.f};
            if (p < PMAX) {
                size_t off = ((size_t)k * PMAX + p) * MM + m0 + mq;
                c = *(const float4*)(cosb + off);
                s = *(const float4*)(sinb + off);
            }
            *(float4*)&cs[pl][mq] = c;
            *(float4*)&ss[pl][mq] = s;
        }
        __syncthreads();

#pragma unroll
        for (int pp = 0; pp < 16; ++pp) {
            float xv[4], cv[4], sv[4];
            *(float4*)xv = *(const float4*)&xs[pp][4 * tx];
            *(float4*)cv = *(const float4*)&cs[pp][4 * ty];
            *(float4*)sv = *(const float4*)&ss[pp][4 * ty];
#pragma unroll
            for (int i = 0; i < 4; ++i)
#pragma unroll
                for (int j = 0; j < 4; ++j) {
                    accr[i][j] += xv[i] * cv[j];
                    acci[i][j] += xv[i] * sv[j];
                }
        }
        __syncthreads();
    }

#pragma unroll
    for (int j = 0; j < 4; ++j) {
        int m = m0 + 4 * ty + j;
        size_t base = ((size_t)m * NLAT + k) * bcc + bct + 4 * tx;
        float4 r = {accr[0][j] * TWO_PI_F, accr[1][j] * TWO_PI_F,
                    accr[2][j] * TWO_PI_F, accr[3][j] * TWO_PI_F};
        float4 s = {acci[0][j] * TWO_PI_F, acci[1][j] * TWO_PI_F,
                    acci[2][j] * TWO_PI_F, acci[3][j] * TWO_PI_F};
        *(float4*)&re_ws[base] = r;
        *(float4*)&im_ws[base] = s;
    }
}

// ---------------------------------------------------------------------------
// Stage 2a: ws2[m][l][bc] = sum_k interm[m][k][bc] * weight[m][l][k]
// Grid: (bcc/64, 3 l-tiles, 192 m).  Block 256.  64(bc) x 64(l) tile, 4x4 micro.
// Writes are coalesced along bc.  Blocks fully below the diagonal (l0+63 < m)
// are skipped entirely; the transpose kernel produces the zero region.
// ---------------------------------------------------------------------------
__global__ __launch_bounds__(256) void sht_stage2(
    const float* __restrict__ ws,
    float* __restrict__ ws2,
    const float* __restrict__ weight,
    int bcc)
{
    const int m   = blockIdx.z;
    const int l0  = blockIdx.y * 64;
    const int bct = blockIdx.x * 64;
    const int tid = threadIdx.x;
    const int tx = tid & 15;                   // -> bc micro
    const int ty = tid >> 4;                   // -> l micro

    if (l0 + 63 < m) return;   // weight == 0 for all l in tile

    const float* __restrict__ re_ws = ws;
    const float* __restrict__ im_ws = ws + (size_t)MM * NLAT * bcc;

    __shared__ float rs[16][64];   // [k][bc]
    __shared__ float is_[16][64];
    __shared__ float wl[16][68];   // [k][l]  padded

    float accr[4][4] = {{0.f}};
    float acci[4][4] = {{0.f}};

    for (int k0 = 0; k0 < NLAT; k0 += 16) {
        {
            int bl = tid & 63;
            int kk = tid >> 6;                 // 0..3
#pragma unroll
            for (int kp = 0; kp < 4; ++kp) {
                int row = kk + kp * 4;
                size_t off = ((size_t)m * NLAT + k0 + row) * bcc + bct + bl;
                rs[row][bl]  = re_ws[off];
                is_[row][bl] = im_ws[off];
            }
        }
        {
            int kk = tid & 15;
            int ll = tid >> 4;                 // 0..15
#pragma unroll
            for (int lp = 0; lp < 4; ++lp) {
                int l = l0 + ll + lp * 16;
                wl[kk][ll + lp * 16] = weight[((size_t)m * LL + l) * NLAT + k0 + kk];
            }
        }
        __syncthreads();

#pragma unroll
        for (int kk = 0; kk < 16; ++kk) {
            float rv[4], iv[4], wv[4];
            *(float4*)rv = *(const float4*)&rs[kk][4 * tx];
            *(float4*)iv = *(const float4*)&is_[kk][4 * tx];
            *(float4*)wv = *(const float4*)&wl[kk][4 * ty];
#pragma unroll
            for (int i = 0; i < 4; ++i)
#pragma unroll
                for (int j = 0; j < 4; ++j) {
                    accr[i][j] += rv[i] * wv[j];
                    acci[i][j] += iv[i] * wv[j];
                }
        }
        __syncthreads();
    }

    float* __restrict__ re2 = ws2;
    float* __restrict__ im2 = ws2 + (size_t)MM * LL * bcc;
#pragma unroll
    for (int j = 0; j < 4; ++j) {
        int l = l0 + 4 * ty + j;
        size_t base = ((size_t)m * LL + l) * bcc + bct + 4 * tx;
        float4 r = {accr[0][j], accr[1][j], accr[2][j], accr[3][j]};
        float4 s = {acci[0][j], acci[1][j], acci[2][j], acci[3][j]};
        *(float4*)&re2[base] = r;
        *(float4*)&im2[base] = s;
    }
}

// ---------------------------------------------------------------------------
// Transpose: out[bc][l][m][2] = {re2[m][l][bc], im2[m][l][bc]}  (0 for m > l)
// Grid: (bcc/32, MM/32 = 6, 192 l).  Block 256.
// Reads coalesced along bc; writes coalesced along m (float2 per lane,
// 32 consecutive lanes -> 256 B contiguous).
// ---------------------------------------------------------------------------
__global__ __launch_bounds__(256) void sht_transpose(
    const float* __restrict__ ws2,
    float* __restrict__ out,
    int bc0, int bcc)
{
    const int l   = blockIdx.z;
    const int m0  = blockIdx.y * 32;
    const int bct = blockIdx.x * 32;
    const int tid = threadIdx.x;

    const float* __restrict__ re2 = ws2;
    const float* __restrict__ im2 = ws2 + (size_t)MM * LL * bcc;

    __shared__ float tr[32][33];
    __shared__ float ti[32][33];

    if (m0 <= l) {
        int bci = tid & 31;
        int mi  = tid >> 5;                    // 0..7
#pragma unroll
        for (int mp = 0; mp < 4; ++mp) {
            int mrow = mi + mp * 8;
            size_t off = ((size_t)(m0 + mrow) * LL + l) * bcc + bct + bci;
            tr[mrow][bci] = re2[off];
            ti[mrow][bci] = im2[off];
        }
    }
    __syncthreads();

    int mi2  = tid & 31;                       // m lane
    int bci2 = tid >> 5;                       // 0..7
    int m = m0 + mi2;
    bool nz = (m <= l);
#pragma unroll
    for (int bcp = 0; bcp < 4; ++bcp) {
        int bcl = bci2 + bcp * 8;
        int bc  = bc0 + bct + bcl;
        float2 v;
        if (nz) { v.x = tr[mi2][bcl]; v.y = ti[mi2][bcl]; }
        else    { v.x = 0.f;          v.y = 0.f;          }
        size_t o = (((size_t)bc * LL + l) * MM + m) * 2;
        *(float2*)&out[o] = v;
    }
}

// ---------------------------------------------------------------------------
extern "C" void kernel_launch(void* const* d_in, const int* in_sizes, int n_in,
                              void* d_out, int out_size, void* d_ws, size_t ws_size,
                              hipStream_t stream)
{
    const float* x      = (const float*)d_in[0];
    const float* weight = (const float*)d_in[1];
    const float* cosb   = (const float*)d_in[2];
    const float* sinb   = (const float*)d_in[3];
    const int*   ring   = (const int*)d_in[4];
    float* out = (float*)d_out;
    float* wsf = (float*)d_ws;

    // Need interm (2*M*K*bcc floats) + ws2 (2*M*L*bcc floats) per chunk.
    const size_t per_bc = 4ull * MM * NLAT * sizeof(float);   // 589824 B per bc column
    int chunk = BC;
    while ((size_t)chunk * per_bc > ws_size && chunk > 64) chunk >>= 1;

    for (int bc0 = 0; bc0 < BC; bc0 += chunk) {
        float* ws2 = wsf + 2ull * MM * NLAT * chunk;
        dim3 grid1(chunk / 64, 3, NLAT);
        hipLaunchKernelGGL(sht_stage1, grid1, dim3(256), 0, stream,
                           x, cosb, sinb, ring, wsf, bc0, chunk);
        dim3 grid2(chunk / 64, 3, MM);
        hipLaunchKernelGGL(sht_stage2, grid2, dim3(256), 0, stream,
                           wsf, ws2, weight, chunk);
        dim3 grid3(chunk / 32, 6, LL);
        hipLaunchKernelGGL(sht_transpose, grid3, dim3(256), 0, stream,
                           ws2, out, bc0, chunk);
    }
}